// Round 5
// baseline (448.672 us; speedup 1.0000x reference)
//
#include <hip/hip_runtime.h>
#include <hip/hip_bf16.h>

typedef __bf16 bf16x8 __attribute__((ext_vector_type(8)));
typedef float f32x4 __attribute__((ext_vector_type(4)));
#define MFMA16 __builtin_amdgcn_mfma_f32_16x16x32_bf16

static constexpr int Bsz = 4, T = 4096, C = 1024, H = 128;
static constexpr int BT = Bsz * T; // 16384

__device__ __forceinline__ void gl2lds16(const __bf16* g, __bf16* l) {
    __builtin_amdgcn_global_load_lds(
        (const __attribute__((address_space(1))) void*)g,
        (__attribute__((address_space(3))) void*)l, 16, 0, 0);
}

// -------- kernel 0: W fp32[1024][128]x3 -> WTall bf16[384][1024] -----------
__global__ __launch_bounds__(256) void k_wprep(
    const float* __restrict__ Wq, const float* __restrict__ Wk,
    const float* __restrict__ Wv, __bf16* __restrict__ WTall)
{
    int idx = blockIdx.x * 256 + threadIdx.x;   // 0..393215
    int n = idx >> 10, k = idx & 1023;
    int mat = n >> 7, col = n & 127;
    const float* W = mat == 0 ? Wq : (mat == 1 ? Wk : Wv);
    float s = (mat == 1) ? 0.045084220f : 1.0f;  // 1/32 * log2(e)
    WTall[idx] = (__bf16)(W[k * H + col] * s);
}

// -------- kernel: zero Out + Pl --------------------------------------------
__global__ __launch_bounds__(256) void k_zero(float* __restrict__ Out,
                                              float* __restrict__ Pl)
{
    int i = blockIdx.x * 256 + threadIdx.x;     // 0..528383
    f32x4 z = (f32x4){0.f, 0.f, 0.f, 0.f};
    if (i < 524288) ((f32x4*)Out)[i] = z;
    else            ((f32x4*)Pl)[i - 524288] = z;
}

// -------- kernel 1: QKV projection GEMM ------------------------------------
__global__ __launch_bounds__(512) void k_proj(
    const float* __restrict__ X, const __bf16* __restrict__ WTall,
    __bf16* __restrict__ Qp, __bf16* __restrict__ Kp, __bf16* __restrict__ VT)
{
    union Smem {
        struct { __bf16 a[2][64 * 64]; __bf16 b[2][384 * 64]; } s; // 112KB
        __bf16 vt_e[128][72];
    };
    __shared__ Smem su;

    const int tid = threadIdx.x;
    const int lane = tid & 63, w = tid >> 6;
    const int c = lane & 15, hi = lane >> 4;
    const int wm = w >> 2, wn = w & 3;
    const int m0 = blockIdx.x * 64;
    const int xorv = (c & 7) << 3;

    const int arow = tid >> 3, ac8 = tid & 7;
    const float* aSrc = X + (size_t)(m0 + arow) * C + ac8 * 8;
    const int aDst = arow * 64 + ((ac8 * 8) ^ ((arow & 7) << 3));
    const int brl = lane >> 3, bch = lane & 7;

    f32x4 acc[2][6];
    #pragma unroll
    for (int i = 0; i < 2; ++i)
        #pragma unroll
        for (int j = 0; j < 6; ++j) acc[i][j] = (f32x4){0.f, 0.f, 0.f, 0.f};

    #pragma unroll
    for (int ib = 0; ib < 6; ++ib) {
        int row = w * 48 + ib * 8 + brl;
        int ch = bch ^ (row & 7);
        gl2lds16(WTall + (size_t)row * 1024 + ch * 8, &su.s.b[0][(w * 6 + ib) * 512]);
    }
    {
        float4 f0 = *(const float4*)aSrc;
        float4 f1 = *(const float4*)(aSrc + 4);
        bf16x8 av;
        av[0] = (__bf16)f0.x; av[1] = (__bf16)f0.y; av[2] = (__bf16)f0.z; av[3] = (__bf16)f0.w;
        av[4] = (__bf16)f1.x; av[5] = (__bf16)f1.y; av[6] = (__bf16)f1.z; av[7] = (__bf16)f1.w;
        *(bf16x8*)&su.s.a[0][aDst] = av;
    }
    __syncthreads();

    for (int t = 0; t < 16; ++t) {
        int cur = t & 1;
        float4 g0, g1;
        if (t < 15) {
            int k0 = (t + 1) * 64;
            #pragma unroll
            for (int ib = 0; ib < 6; ++ib) {
                int row = w * 48 + ib * 8 + brl;
                int ch = bch ^ (row & 7);
                gl2lds16(WTall + (size_t)row * 1024 + k0 + ch * 8,
                         &su.s.b[cur ^ 1][(w * 6 + ib) * 512]);
            }
            g0 = *(const float4*)(aSrc + k0);
            g1 = *(const float4*)(aSrc + k0 + 4);
        }
        #pragma unroll
        for (int kk = 0; kk < 2; ++kk) {
            bf16x8 a0 = *(const bf16x8*)&su.s.a[cur][(wm * 32 + c) * 64 + ((kk * 32 + hi * 8) ^ xorv)];
            bf16x8 a1 = *(const bf16x8*)&su.s.a[cur][(wm * 32 + 16 + c) * 64 + ((kk * 32 + hi * 8) ^ xorv)];
            #pragma unroll
            for (int fn = 0; fn < 6; ++fn) {
                bf16x8 bb = *(const bf16x8*)&su.s.b[cur][(wn * 96 + fn * 16 + c) * 64 + ((kk * 32 + hi * 8) ^ xorv)];
                acc[0][fn] = MFMA16(a0, bb, acc[0][fn], 0, 0, 0);
                acc[1][fn] = MFMA16(a1, bb, acc[1][fn], 0, 0, 0);
            }
        }
        if (t < 15) {
            bf16x8 av;
            av[0] = (__bf16)g0.x; av[1] = (__bf16)g0.y; av[2] = (__bf16)g0.z; av[3] = (__bf16)g0.w;
            av[4] = (__bf16)g1.x; av[5] = (__bf16)g1.y; av[6] = (__bf16)g1.z; av[7] = (__bf16)g1.w;
            *(bf16x8*)&su.s.a[cur ^ 1][aDst] = av;
        }
        __syncthreads();
    }

    #pragma unroll
    for (int mi = 0; mi < 2; ++mi) {
        int rowl = wm * 32 + mi * 16 + hi * 4;
        #pragma unroll
        for (int fn = 0; fn < 6; ++fn) {
            int nb = wn * 96 + fn * 16;
            int mat = nb >> 7, colb = (nb & 127) + c;
            #pragma unroll
            for (int r = 0; r < 4; ++r) {
                __bf16 v = (__bf16)acc[mi][fn][r];
                if (mat == 0)      Qp[(size_t)(m0 + rowl + r) * H + colb] = v;
                else if (mat == 1) Kp[(size_t)(m0 + rowl + r) * H + colb] = v;
                else               su.vt_e[colb][rowl + r] = v;
            }
        }
    }
    __syncthreads();
    {
        int d = tid >> 2, tc = (tid & 3) * 16;
        int b = m0 >> 12, tl = m0 & (T - 1);
        __bf16* dst = VT + ((size_t)b * H + d) * T + tl + tc;
        const __bf16* s2 = &su.vt_e[d][tc];
        *(uint4*)dst = *(const uint4*)s2;
        *(uint4*)(dst + 8) = *(const uint4*)(s2 + 8);
    }
}

// -------- kernel 2: causal attention ---------------------------------------
// 256 blocks = 4 parts x 4 batches x 16 pairs. Block: 8 waves (4m x 2s-half),
// 128 q-rows, tile pair {j, 31-j}; part p takes s-steps i = p, p+4, ...
// Partial O / row-sums atomically accumulated into Out / Pl.
__global__ __launch_bounds__(512) void k_attn(
    const __bf16* __restrict__ Ka, const __bf16* __restrict__ Qb,
    const __bf16* __restrict__ VT, float* __restrict__ Out,
    float* __restrict__ Pl)
{
    union SMem {
        struct { __bf16 q[2][64 * 128]; __bf16 v[2][128 * 64]; } s; // 64KB
        float oacc[128][133];                                       // 68KB
    };
    __shared__ SMem su;
    __shared__ __bf16 pl[8][32][40];
    __shared__ float sml[8][32];

    const int tid = threadIdx.x, lane = tid & 63, w = tid >> 6;
    const int c = lane & 15, hi = lane >> 4;
    const int wm = w >> 1, ws = w & 1;
    const int xorq = c << 3;
    const int xorv = (c & 7) << 3;

    const int bi = blockIdx.x;
    const int p = bi & 3, b = (bi >> 2) & 3, j = bi >> 4;   // j in 0..15

    const __bf16* Kb  = Ka + (size_t)b * T * H;
    const __bf16* Qbb = Qb + (size_t)b * T * H;
    const __bf16* Vb  = VT + (size_t)b * H * T;

    bf16x8 ones;
    #pragma unroll
    for (int q8 = 0; q8 < 8; ++q8) ones[q8] = (__bf16)1.0f;

    #pragma unroll 1
    for (int half = 0; half < 2; ++half) {
        const int jj = half ? (31 - j) : j;
        const int t0 = jj * 128;
        const int nsteps = 2 * jj + 2;

        bf16x8 af[2][4];
        #pragma unroll
        for (int mi = 0; mi < 2; ++mi)
            #pragma unroll
            for (int kc = 0; kc < 4; ++kc)
                af[mi][kc] = *(const bf16x8*)(Kb + (size_t)(t0 + wm * 32 + mi * 16 + c) * H + kc * 32 + hi * 8);

        f32x4 o[2][8], ol[2];
        #pragma unroll
        for (int mi = 0; mi < 2; ++mi) {
            #pragma unroll
            for (int nt = 0; nt < 8; ++nt) o[mi][nt] = (f32x4){0.f, 0.f, 0.f, 0.f};
            ol[mi] = (f32x4){0.f, 0.f, 0.f, 0.f};
        }

        __syncthreads();   // prev epilogue's oacc reads done (union alias)

        int i = p, cur = 0;
        if (i < nsteps) {
            int s0 = i * 64;
            #pragma unroll
            for (int iq = 0; iq < 2; ++iq) {
                int row = (w * 2 + iq) * 4 + (lane >> 4);
                int ch = (lane & 15) ^ (row & 15);
                gl2lds16(Qbb + (size_t)(s0 + row) * H + ch * 8, &su.s.q[0][(w * 2 + iq) * 512]);
            }
            #pragma unroll
            for (int iv = 0; iv < 2; ++iv) {
                int d = (w * 2 + iv) * 8 + (lane >> 3);
                int ch = (lane & 7) ^ (d & 7);
                gl2lds16(Vb + (size_t)d * T + s0 + ch * 8, &su.s.v[0][(w * 2 + iv) * 512]);
            }
        }
        __syncthreads();

        while (i < nsteps) {
            const int s0 = i * 64;
            const int inext = i + 4;
            if (inext < nsteps) {
                int sn = inext * 64;
                #pragma unroll
                for (int iq = 0; iq < 2; ++iq) {
                    int row = (w * 2 + iq) * 4 + (lane >> 4);
                    int ch = (lane & 15) ^ (row & 15);
                    gl2lds16(Qbb + (size_t)(sn + row) * H + ch * 8, &su.s.q[cur ^ 1][(w * 2 + iq) * 512]);
                }
                #pragma unroll
                for (int iv = 0; iv < 2; ++iv) {
                    int d = (w * 2 + iv) * 8 + (lane >> 3);
                    int ch = (lane & 7) ^ (d & 7);
                    gl2lds16(Vb + (size_t)d * T + sn + ch * 8, &su.s.v[cur ^ 1][(w * 2 + iv) * 512]);
                }
            }
            f32x4 sa[2][2];
            sa[0][0] = (f32x4){0.f, 0.f, 0.f, 0.f}; sa[0][1] = sa[0][0];
            sa[1][0] = sa[0][0]; sa[1][1] = sa[0][0];
            #pragma unroll
            for (int kc = 0; kc < 4; ++kc) {
                bf16x8 b0 = *(const bf16x8*)&su.s.q[cur][(ws * 32 + c) * 128 + ((kc * 32 + hi * 8) ^ xorq)];
                bf16x8 b1 = *(const bf16x8*)&su.s.q[cur][(ws * 32 + 16 + c) * 128 + ((kc * 32 + hi * 8) ^ xorq)];
                sa[0][0] = MFMA16(af[0][kc], b0, sa[0][0], 0, 0, 0);
                sa[0][1] = MFMA16(af[0][kc], b1, sa[0][1], 0, 0, 0);
                sa[1][0] = MFMA16(af[1][kc], b0, sa[1][0], 0, 0, 0);
                sa[1][1] = MFMA16(af[1][kc], b1, sa[1][1], 0, 0, 0);
            }
            const bool dz = (s0 + 63 >= t0);
            #pragma unroll
            for (int mi = 0; mi < 2; ++mi)
                #pragma unroll
                for (int ni = 0; ni < 2; ++ni) {
                    int sg = s0 + ws * 32 + ni * 16 + c;
                    #pragma unroll
                    for (int r = 0; r < 4; ++r) {
                        float e = __builtin_amdgcn_exp2f(sa[mi][ni][r]);
                        if (dz) {
                            int tg = t0 + wm * 32 + mi * 16 + hi * 4 + r;
                            if (sg > tg) e = 0.f;
                        }
                        pl[w][mi * 16 + hi * 4 + r][ni * 16 + c] = (__bf16)e;
                    }
                }
            bf16x8 pf0 = *(const bf16x8*)&pl[w][c][hi * 8];
            bf16x8 pf1 = *(const bf16x8*)&pl[w][16 + c][hi * 8];
            ol[0] = MFMA16(pf0, ones, ol[0], 0, 0, 0);
            ol[1] = MFMA16(pf1, ones, ol[1], 0, 0, 0);
            #pragma unroll
            for (int nt = 0; nt < 8; ++nt) {
                bf16x8 vb = *(const bf16x8*)&su.s.v[cur][(nt * 16 + c) * 64 + ((ws * 32 + hi * 8) ^ xorv)];
                o[0][nt] = MFMA16(pf0, vb, o[0][nt], 0, 0, 0);
                o[1][nt] = MFMA16(pf1, vb, o[1][nt], 0, 0, 0);
            }
            __syncthreads();
            cur ^= 1;
            i = inext;
        }

        // merge ws pairs via LDS, then atomic-accumulate to global
        if (c == 0) {
            #pragma unroll
            for (int mi = 0; mi < 2; ++mi)
                #pragma unroll
                for (int r = 0; r < 4; ++r)
                    sml[w][mi * 16 + hi * 4 + r] = ol[mi][r];
        }
        if (ws == 0) {
            #pragma unroll
            for (int mi = 0; mi < 2; ++mi)
                #pragma unroll
                for (int nt = 0; nt < 8; ++nt)
                    #pragma unroll
                    for (int r = 0; r < 4; ++r)
                        su.oacc[wm * 32 + mi * 16 + hi * 4 + r][nt * 16 + c] = o[mi][nt][r];
        }
        __syncthreads();
        if (ws == 1) {
            #pragma unroll
            for (int mi = 0; mi < 2; ++mi)
                #pragma unroll
                for (int nt = 0; nt < 8; ++nt)
                    #pragma unroll
                    for (int r = 0; r < 4; ++r)
                        su.oacc[wm * 32 + mi * 16 + hi * 4 + r][nt * 16 + c] += o[mi][nt][r];
        }
        __syncthreads();
        {
            int row = tid >> 2, col0 = (tid & 3) * 32;
            float L = sml[(row >> 5) * 2][row & 31] + sml[(row >> 5) * 2 + 1][row & 31];
            float* dst = Out + ((size_t)b * T + t0 + row) * H + col0;
            #pragma unroll
            for (int q8 = 0; q8 < 32; ++q8)
                atomicAdd(dst + q8, su.oacc[row][col0 + q8]);
            if ((tid & 3) == 0)
                atomicAdd(&Pl[(size_t)b * T + t0 + row], L);
        }
    }
}

// -------- kernel 3: normalize in place --------------------------------------
__global__ __launch_bounds__(256) void k_norm(
    float* __restrict__ Out, const float* __restrict__ Pl)
{
    size_t idx = ((size_t)blockIdx.x * 256 + threadIdx.x) * 8;
    size_t row = idx >> 7;
    float inv = 1.0f / Pl[row];
    float4 a0 = *(const float4*)(Out + idx);
    float4 a1 = *(const float4*)(Out + idx + 4);
    a0.x *= inv; a0.y *= inv; a0.z *= inv; a0.w *= inv;
    a1.x *= inv; a1.y *= inv; a1.z *= inv; a1.w *= inv;
    *(float4*)(Out + idx)     = a0;
    *(float4*)(Out + idx + 4) = a1;
}

extern "C" void kernel_launch(void* const* d_in, const int* in_sizes, int n_in,
                              void* d_out, int out_size, void* d_ws, size_t ws_size,
                              hipStream_t stream) {
    const float* ix = (const float*)d_in[0];
    const float* Wq = (const float*)d_in[1];
    const float* Wk = (const float*)d_in[2];
    const float* Wv = (const float*)d_in[3];
    float* out = (float*)d_out;

    __bf16* WTall = (__bf16*)d_ws;                    // 384*1024
    __bf16* Qp = WTall + 393216;                      // [BT][H]
    __bf16* Kp = Qp + (size_t)BT * H;
    __bf16* VT = Kp + (size_t)BT * H;                 // [B][H][T]
    float*  Pl = (float*)(VT + (size_t)BT * H);       // [BT]
    // total ws ~12.8 MB

    k_wprep<<<dim3(1536), 256, 0, stream>>>(Wq, Wk, Wv, WTall);
    k_zero<<<dim3(2064), 256, 0, stream>>>(out, Pl);
    k_proj<<<dim3(256), 512, 0, stream>>>(ix, WTall, Qp, Kp, VT);
    k_attn<<<dim3(256), 512, 0, stream>>>(Kp, Qp, VT, out, Pl);
    k_norm<<<dim3(1024), 256, 0, stream>>>(out, Pl);
}

// Round 6
// 123.560 us; speedup vs baseline: 3.6312x; 3.6312x over previous
//
#include <hip/hip_runtime.h>
#include <hip/hip_bf16.h>

typedef __bf16 bf16x8 __attribute__((ext_vector_type(8)));
typedef float f32x4 __attribute__((ext_vector_type(4)));
#define MFMA16 __builtin_amdgcn_mfma_f32_16x16x32_bf16

static constexpr int Bsz = 4, T = 4096, C = 1024, H = 128;
static constexpr int BT = Bsz * T; // 16384

__device__ __forceinline__ void gl2lds16(const __bf16* g, __bf16* l) {
    __builtin_amdgcn_global_load_lds(
        (const __attribute__((address_space(1))) void*)g,
        (__attribute__((address_space(3))) void*)l, 16, 0, 0);
}

// -------- kernel 0: W fp32[1024][128]x3 -> WTall bf16[384][1024] -----------
__global__ __launch_bounds__(256) void k_wprep(
    const float* __restrict__ Wq, const float* __restrict__ Wk,
    const float* __restrict__ Wv, __bf16* __restrict__ WTall)
{
    int idx = blockIdx.x * 256 + threadIdx.x;   // 0..393215
    int n = idx >> 10, k = idx & 1023;
    int mat = n >> 7, col = n & 127;
    const float* W = mat == 0 ? Wq : (mat == 1 ? Wk : Wv);
    float s = (mat == 1) ? 0.045084220f : 1.0f;  // 1/32 * log2(e)
    WTall[idx] = (__bf16)(W[k * H + col] * s);
}

// -------- kernel 1: QKV projection GEMM ------------------------------------
__global__ __launch_bounds__(512) void k_proj(
    const float* __restrict__ X, const __bf16* __restrict__ WTall,
    __bf16* __restrict__ Qp, __bf16* __restrict__ Kp, __bf16* __restrict__ VT)
{
    union Smem {
        struct { __bf16 a[2][64 * 64]; __bf16 b[2][384 * 64]; } s; // 112KB
        __bf16 vt_e[128][72];
    };
    __shared__ Smem su;

    const int tid = threadIdx.x;
    const int lane = tid & 63, w = tid >> 6;
    const int c = lane & 15, hi = lane >> 4;
    const int wm = w >> 2, wn = w & 3;
    const int m0 = blockIdx.x * 64;
    const int xorv = (c & 7) << 3;

    const int arow = tid >> 3, ac8 = tid & 7;
    const float* aSrc = X + (size_t)(m0 + arow) * C + ac8 * 8;
    const int aDst = arow * 64 + ((ac8 * 8) ^ ((arow & 7) << 3));
    const int brl = lane >> 3, bch = lane & 7;

    f32x4 acc[2][6];
    #pragma unroll
    for (int i = 0; i < 2; ++i)
        #pragma unroll
        for (int j = 0; j < 6; ++j) acc[i][j] = (f32x4){0.f, 0.f, 0.f, 0.f};

    #pragma unroll
    for (int ib = 0; ib < 6; ++ib) {
        int row = w * 48 + ib * 8 + brl;
        int ch = bch ^ (row & 7);
        gl2lds16(WTall + (size_t)row * 1024 + ch * 8, &su.s.b[0][(w * 6 + ib) * 512]);
    }
    {
        float4 f0 = *(const float4*)aSrc;
        float4 f1 = *(const float4*)(aSrc + 4);
        bf16x8 av;
        av[0] = (__bf16)f0.x; av[1] = (__bf16)f0.y; av[2] = (__bf16)f0.z; av[3] = (__bf16)f0.w;
        av[4] = (__bf16)f1.x; av[5] = (__bf16)f1.y; av[6] = (__bf16)f1.z; av[7] = (__bf16)f1.w;
        *(bf16x8*)&su.s.a[0][aDst] = av;
    }
    __syncthreads();

    for (int t = 0; t < 16; ++t) {
        int cur = t & 1;
        float4 g0, g1;
        if (t < 15) {
            int k0 = (t + 1) * 64;
            #pragma unroll
            for (int ib = 0; ib < 6; ++ib) {
                int row = w * 48 + ib * 8 + brl;
                int ch = bch ^ (row & 7);
                gl2lds16(WTall + (size_t)row * 1024 + k0 + ch * 8,
                         &su.s.b[cur ^ 1][(w * 6 + ib) * 512]);
            }
            g0 = *(const float4*)(aSrc + k0);
            g1 = *(const float4*)(aSrc + k0 + 4);
        }
        #pragma unroll
        for (int kk = 0; kk < 2; ++kk) {
            bf16x8 a0 = *(const bf16x8*)&su.s.a[cur][(wm * 32 + c) * 64 + ((kk * 32 + hi * 8) ^ xorv)];
            bf16x8 a1 = *(const bf16x8*)&su.s.a[cur][(wm * 32 + 16 + c) * 64 + ((kk * 32 + hi * 8) ^ xorv)];
            #pragma unroll
            for (int fn = 0; fn < 6; ++fn) {
                bf16x8 bb = *(const bf16x8*)&su.s.b[cur][(wn * 96 + fn * 16 + c) * 64 + ((kk * 32 + hi * 8) ^ xorv)];
                acc[0][fn] = MFMA16(a0, bb, acc[0][fn], 0, 0, 0);
                acc[1][fn] = MFMA16(a1, bb, acc[1][fn], 0, 0, 0);
            }
        }
        if (t < 15) {
            bf16x8 av;
            av[0] = (__bf16)g0.x; av[1] = (__bf16)g0.y; av[2] = (__bf16)g0.z; av[3] = (__bf16)g0.w;
            av[4] = (__bf16)g1.x; av[5] = (__bf16)g1.y; av[6] = (__bf16)g1.z; av[7] = (__bf16)g1.w;
            *(bf16x8*)&su.s.a[cur ^ 1][aDst] = av;
        }
        __syncthreads();
    }

    #pragma unroll
    for (int mi = 0; mi < 2; ++mi) {
        int rowl = wm * 32 + mi * 16 + hi * 4;
        #pragma unroll
        for (int fn = 0; fn < 6; ++fn) {
            int nb = wn * 96 + fn * 16;
            int mat = nb >> 7, colb = (nb & 127) + c;
            #pragma unroll
            for (int r = 0; r < 4; ++r) {
                __bf16 v = (__bf16)acc[mi][fn][r];
                if (mat == 0)      Qp[(size_t)(m0 + rowl + r) * H + colb] = v;
                else if (mat == 1) Kp[(size_t)(m0 + rowl + r) * H + colb] = v;
                else               su.vt_e[colb][rowl + r] = v;
            }
        }
    }
    __syncthreads();
    {
        int d = tid >> 2, tc = (tid & 3) * 16;
        int b = m0 >> 12, tl = m0 & (T - 1);
        __bf16* dst = VT + ((size_t)b * H + d) * T + tl + tc;
        const __bf16* s2 = &su.vt_e[d][tc];
        *(uint4*)dst = *(const uint4*)s2;
        *(uint4*)(dst + 8) = *(const uint4*)(s2 + 8);
    }
}

// -------- kernel 2: causal attention ---------------------------------------
// 256 blocks = 2 parts x 4 batches x 32 pairs of 64-row q-tiles {j, 63-j}.
// Block: 8 waves = 4 m-groups (16 rows) x 2 s-halves (32 of 64 s-cols).
// Part p takes s-steps i = p, p+2, ... Per-part unnormalized O + row sums;
// no atomics. bi&7 = (p<<2)|b pins (part,batch) per XCD (Q+V = 2MB fits L2).
__global__ __launch_bounds__(512) void k_attn(
    const __bf16* __restrict__ Ka, const __bf16* __restrict__ Qb,
    const __bf16* __restrict__ VT, float* __restrict__ Out,
    float* __restrict__ Po, float* __restrict__ Pl)
{
    union SMem {
        struct { __bf16 q[2][64 * 128]; __bf16 v[2][128 * 64]; } s; // 64KB
        float oacc[64][132];                                        // 33.8KB
    };
    __shared__ SMem su;
    __shared__ __bf16 pl[8][16][40];
    __shared__ float sml[8][16];

    const int tid = threadIdx.x, lane = tid & 63, w = tid >> 6;
    const int c = lane & 15, hi = lane >> 4;
    const int wm = w >> 1, ws = w & 1;
    const int xorq = c << 3;
    const int xorv = (c & 7) << 3;

    const int bi = blockIdx.x;
    const int b = bi & 3, p = (bi >> 2) & 1, j = bi >> 3;   // j in 0..31

    const __bf16* Kb  = Ka + (size_t)b * T * H;
    const __bf16* Qbb = Qb + (size_t)b * T * H;
    const __bf16* Vb  = VT + (size_t)b * H * T;

    bf16x8 ones;
    #pragma unroll
    for (int q8 = 0; q8 < 8; ++q8) ones[q8] = (__bf16)1.0f;

    #pragma unroll 1
    for (int half = 0; half < 2; ++half) {
        const int jj = half ? (63 - j) : j;
        const int t0 = jj * 64;
        const int nsteps = jj + 1;          // 64-col s-steps

        // A fragments: this wave's 16 K-rows, full H (held in 16 VGPRs)
        bf16x8 af[4];
        #pragma unroll
        for (int kc = 0; kc < 4; ++kc)
            af[kc] = *(const bf16x8*)(Kb + (size_t)(t0 + wm * 16 + c) * H + kc * 32 + hi * 8);

        f32x4 o[8], ol;
        #pragma unroll
        for (int nt = 0; nt < 8; ++nt) o[nt] = (f32x4){0.f, 0.f, 0.f, 0.f};
        ol = (f32x4){0.f, 0.f, 0.f, 0.f};

        __syncthreads();   // prev epilogue's oacc reads done (union alias)

        int i = p, cur = 0;
        if (i < nsteps) {
            int s0 = i * 64;
            #pragma unroll
            for (int iq = 0; iq < 2; ++iq) {
                int row = (w * 2 + iq) * 4 + (lane >> 4);
                int ch = (lane & 15) ^ (row & 15);
                gl2lds16(Qbb + (size_t)(s0 + row) * H + ch * 8, &su.s.q[0][(w * 2 + iq) * 512]);
            }
            #pragma unroll
            for (int iv = 0; iv < 2; ++iv) {
                int d = (w * 2 + iv) * 8 + (lane >> 3);
                int ch = (lane & 7) ^ (d & 7);
                gl2lds16(Vb + (size_t)d * T + s0 + ch * 8, &su.s.v[0][(w * 2 + iv) * 512]);
            }
        }
        __syncthreads();

        while (i < nsteps) {
            const int s0 = i * 64;
            const int inext = i + 2;
            if (inext < nsteps) {
                int sn = inext * 64;
                #pragma unroll
                for (int iq = 0; iq < 2; ++iq) {
                    int row = (w * 2 + iq) * 4 + (lane >> 4);
                    int ch = (lane & 15) ^ (row & 15);
                    gl2lds16(Qbb + (size_t)(sn + row) * H + ch * 8, &su.s.q[cur ^ 1][(w * 2 + iq) * 512]);
                }
                #pragma unroll
                for (int iv = 0; iv < 2; ++iv) {
                    int d = (w * 2 + iv) * 8 + (lane >> 3);
                    int ch = (lane & 7) ^ (d & 7);
                    gl2lds16(Vb + (size_t)d * T + sn + ch * 8, &su.s.v[cur ^ 1][(w * 2 + iv) * 512]);
                }
            }
            // QK^T: wave's 16 rows x its 32 s-cols
            f32x4 sa0 = (f32x4){0.f, 0.f, 0.f, 0.f};
            f32x4 sa1 = (f32x4){0.f, 0.f, 0.f, 0.f};
            #pragma unroll
            for (int kc = 0; kc < 4; ++kc) {
                bf16x8 b0 = *(const bf16x8*)&su.s.q[cur][(ws * 32 + c) * 128 + ((kc * 32 + hi * 8) ^ xorq)];
                bf16x8 b1 = *(const bf16x8*)&su.s.q[cur][(ws * 32 + 16 + c) * 128 + ((kc * 32 + hi * 8) ^ xorq)];
                sa0 = MFMA16(af[kc], b0, sa0, 0, 0, 0);
                sa1 = MFMA16(af[kc], b1, sa1, 0, 0, 0);
            }
            // exp2 + causal mask -> P (bf16) in per-wave LDS
            const bool dz = (i == nsteps - 1) && (s0 + 63 >= t0);
            #pragma unroll
            for (int r = 0; r < 4; ++r) {
                float e0 = __builtin_amdgcn_exp2f(sa0[r]);
                float e1 = __builtin_amdgcn_exp2f(sa1[r]);
                if (dz) {
                    int tg = t0 + wm * 16 + hi * 4 + r;
                    if (s0 + ws * 32 + c > tg)      e0 = 0.f;
                    if (s0 + ws * 32 + 16 + c > tg) e1 = 0.f;
                }
                pl[w][hi * 4 + r][c]      = (__bf16)e0;
                pl[w][hi * 4 + r][16 + c] = (__bf16)e1;
            }
            bf16x8 pf = *(const bf16x8*)&pl[w][c][hi * 8];
            ol = MFMA16(pf, ones, ol, 0, 0, 0);
            #pragma unroll
            for (int nt = 0; nt < 8; ++nt) {
                bf16x8 vb = *(const bf16x8*)&su.s.v[cur][(nt * 16 + c) * 64 + ((ws * 32 + hi * 8) ^ xorv)];
                o[nt] = MFMA16(pf, vb, o[nt], 0, 0, 0);
            }
            __syncthreads();
            cur ^= 1;
            i = inext;
        }

        // ---- merge the two s-halves via LDS; store unnormalized ----
        if (c == 0) {
            #pragma unroll
            for (int r = 0; r < 4; ++r) sml[w][hi * 4 + r] = ol[r];
        }
        if (ws == 0) {
            #pragma unroll
            for (int nt = 0; nt < 8; ++nt)
                #pragma unroll
                for (int r = 0; r < 4; ++r)
                    su.oacc[wm * 16 + hi * 4 + r][nt * 16 + c] = o[nt][r];
        }
        __syncthreads();
        if (ws == 1) {
            #pragma unroll
            for (int nt = 0; nt < 8; ++nt)
                #pragma unroll
                for (int r = 0; r < 4; ++r)
                    su.oacc[wm * 16 + hi * 4 + r][nt * 16 + c] += o[nt][r];
        }
        __syncthreads();
        {
            int row = tid >> 3, col0 = (tid & 7) * 16;
            float L = sml[(row >> 4) * 2][row & 15] + sml[(row >> 4) * 2 + 1][row & 15];
            float* dst = (p == 0 ? Out : Po) + ((size_t)b * T + t0 + row) * H + col0;
            #pragma unroll
            for (int q8 = 0; q8 < 16; q8 += 4) {
                float4 v;
                v.x = su.oacc[row][col0 + q8];
                v.y = su.oacc[row][col0 + q8 + 1];
                v.z = su.oacc[row][col0 + q8 + 2];
                v.w = su.oacc[row][col0 + q8 + 3];
                *(float4*)(dst + q8) = v;
            }
            if ((tid & 7) == 0) Pl[(size_t)p * BT + b * T + t0 + row] = L;
        }
    }
}

// -------- kernel 3: merge parts + normalize --------------------------------
__global__ __launch_bounds__(256) void k_merge(
    float* __restrict__ Out, const float* __restrict__ Po,
    const float* __restrict__ Pl)
{
    size_t idx = ((size_t)blockIdx.x * 256 + threadIdx.x) * 8;
    size_t row = idx >> 7;
    float inv = 1.0f / (Pl[row] + Pl[BT + row]);
    float4 a0 = *(const float4*)(Out + idx);
    float4 a1 = *(const float4*)(Out + idx + 4);
    float4 p0 = *(const float4*)(Po + idx);
    float4 p1 = *(const float4*)(Po + idx + 4);
    float4 r0, r1;
    r0.x = (a0.x + p0.x) * inv; r0.y = (a0.y + p0.y) * inv;
    r0.z = (a0.z + p0.z) * inv; r0.w = (a0.w + p0.w) * inv;
    r1.x = (a1.x + p1.x) * inv; r1.y = (a1.y + p1.y) * inv;
    r1.z = (a1.z + p1.z) * inv; r1.w = (a1.w + p1.w) * inv;
    *(float4*)(Out + idx)     = r0;
    *(float4*)(Out + idx + 4) = r1;
}

extern "C" void kernel_launch(void* const* d_in, const int* in_sizes, int n_in,
                              void* d_out, int out_size, void* d_ws, size_t ws_size,
                              hipStream_t stream) {
    const float* ix = (const float*)d_in[0];
    const float* Wq = (const float*)d_in[1];
    const float* Wk = (const float*)d_in[2];
    const float* Wv = (const float*)d_in[3];
    float* out = (float*)d_out;

    __bf16* WTall = (__bf16*)d_ws;                    // 384*1024
    __bf16* Qp = WTall + 393216;                      // [BT][H]
    __bf16* Kp = Qp + (size_t)BT * H;
    __bf16* VT = Kp + (size_t)BT * H;                 // [B][H][T]
    float*  Po = (float*)(VT + (size_t)BT * H);       // [BT][H] fp32
    float*  Pl = Po + (size_t)BT * H;                 // [2][BT]
    // total ws ~21.9 MB (same as round 3, known-good)

    k_wprep<<<dim3(1536), 256, 0, stream>>>(Wq, Wk, Wv, WTall);
    k_proj<<<dim3(256), 512, 0, stream>>>(ix, WTall, Qp, Kp, VT);
    k_attn<<<dim3(256), 512, 0, stream>>>(Kp, Qp, VT, out, Po, Pl);
    k_merge<<<dim3(1024), 256, 0, stream>>>(out, Po, Pl);
}